// Round 1
// 257.055 us; speedup vs baseline: 1.0104x; 1.0104x over previous
//
#include <hip/hip_runtime.h>
#include <stdint.h>

// ClusteringLayer: q = rownorm(1/(1 + ||x||^2 + ||c||^2 - 2 x@c^T))
// N=65536, D=512, K=512.
// v2: latency-bound fix. B (512KB, L2-resident) is no longer LDS-staged —
// fragments are read directly from a fragment-major global image (coalesced
// 1KB/wave). A is double-buffered in LDS with raw s_barrier (lgkmcnt-only
// fence, NO vmcnt drain), and loads are issued in FIFO-aware order so the
// x-prefetch stays in flight across the barrier. Epilogue transposes through
// the freed LDS for contiguous float4 stores.

#define D 512
#define K 512
#define BM 64
#define BK 64          // D-chunk per stage
#define NCHUNK (D / BK)
#define THREADS 512
#define ESTRIDE 516    // padded f32 row stride for the epilogue transpose buf

typedef __attribute__((ext_vector_type(8))) short short8;   // 8 x bf16
typedef __attribute__((ext_vector_type(4))) float floatx4;  // MFMA acc

// fp32 -> bf16 round-to-nearest-even
__device__ __forceinline__ uint16_t f2bf(float f) {
  uint32_t u = __float_as_uint(f);
  u += 0x7FFFu + ((u >> 16) & 1u);
  return (uint16_t)(u >> 16);
}

__device__ __forceinline__ uint4 pack8(float4 v0, float4 v1) {
  uint4 pk;
  pk.x = (uint32_t)f2bf(v0.x) | ((uint32_t)f2bf(v0.y) << 16);
  pk.y = (uint32_t)f2bf(v0.z) | ((uint32_t)f2bf(v0.w) << 16);
  pk.z = (uint32_t)f2bf(v1.x) | ((uint32_t)f2bf(v1.y) << 16);
  pk.w = (uint32_t)f2bf(v1.z) | ((uint32_t)f2bf(v1.w) << 16);
  return pk;
}

__device__ __forceinline__ float sq8(float4 v0, float4 v1) {
  return v0.x*v0.x + v0.y*v0.y + v0.z*v0.z + v0.w*v0.w
       + v1.x*v1.x + v1.y*v1.y + v1.z*v1.z + v1.w*v1.w;
}

// ---------------------------------------------------------------------------
// Prep: centroids fp32 -> bf16 in a FRAGMENT-MAJOR layout for direct global
// MFMA-fragment reads (B never touches LDS in the main kernel):
//   16B slot = ((c*2 + kk)*512 + row)*4 + quad
// A wave's fragment read (fixed c,kk,ni) hits slots
//   ((c*2+kk)*512 + w*64+ni*16+p)*4 + quad  for p=0..15, quad=0..3
// = 16 consecutive rows x 4 quads = one contiguous, perfectly-coalesced 1KB.
// Also ||c||^2 per centroid.
// ---------------------------------------------------------------------------
__global__ __launch_bounds__(64)
void prep_kernel(const float* __restrict__ cent, float* __restrict__ csq,
                 uint16_t* __restrict__ bbf) {
  const int row  = blockIdx.x;     // 0..511
  const int lane = threadIdx.x;    // 0..63, 8 floats each
  const float4* src = (const float4*)(cent + (size_t)row * D + lane * 8);
  float4 v0 = src[0];
  float4 v1 = src[1];
  float ss = sq8(v0, v1);
  uint4 pk = pack8(v0, v1);
  const int c = lane >> 3;         // D-chunk
  const int g = lane & 7;          // 8-col group within chunk: g = kk*4 + quad
  const int slot = ((c * 2 + (g >> 2)) * 512 + row) * 4 + (g & 3);
  *(uint4*)(bbf + (size_t)slot * 8) = pk;
  #pragma unroll
  for (int m = 1; m < 64; m <<= 1) ss += __shfl_xor(ss, m);
  if (lane == 0) csq[row] = ss;
}

// ---------------------------------------------------------------------------
// Main fused kernel. Block = 64 rows x all 512 centroids, 8 waves;
// wave w owns cols [64w, 64w+64): 4x4 grid of 16x16x32 bf16 MFMA.
// ---------------------------------------------------------------------------
__global__ __launch_bounds__(THREADS, 4)
void cluster_main(const float* __restrict__ x, const uint16_t* __restrict__ bbf,
                  const float* __restrict__ csq, float* __restrict__ out) {
  // smem: main loop uses it as lA[2][64*64] bf16 (16KB, double-buffered,
  // XOR-swizzled); epilogue reuses it as a [32][516] f32 transpose buffer
  // (66KB). 66.5KB total LDS -> 2 blocks/CU.
  __shared__ __align__(16) char smem[32 * ESTRIDE * 4];
  __shared__ float lxsq[BM];
  __shared__ float lrow[BM];
  uint16_t* const lA = (uint16_t*)smem;
  float* const ebuf  = (float*)smem;

  const int tid  = threadIdx.x;
  const int wave = tid >> 6;
  const int lane = tid & 63;
  const int p    = lane & 15;     // MFMA row/col-within-16
  const int quad = lane >> 4;     // MFMA quad
  const int row0 = blockIdx.x * BM;

  if (tid < BM) lrow[tid] = 0.f;

  // A staging assignment (chunk-invariant): thread -> (row ar, 8-col group ag)
  const int ar = tid >> 3;        // 0..63
  const int ag = tid & 7;
  const int adst = (ar * 8 + (ag ^ (ar & 7))) * 8;   // u16 offset, XOR swizzle
  const float* xp = x + (size_t)(row0 + ar) * D + ag * 8;
  float xacc = 0.f;               // partial ||x||^2 for row ar

  // per-lane B base (u16 units) into the fragment-major image
  const uint16_t* const bl = bbf + ((wave * 64 + p) * 32 + quad * 8);

  floatx4 acc[4][4];
  #pragma unroll
  for (int mi = 0; mi < 4; ++mi)
    #pragma unroll
    for (int ni = 0; ni < 4; ++ni)
      acc[mi][ni] = (floatx4){0.f, 0.f, 0.f, 0.f};

  // ---- prologue: chunk 0 -> lA[0]; then issue chunk-1 x loads, which stay
  // in flight across the raw barrier (no vmcnt drain) ----
  {
    float4 pv0 = *(const float4*)xp;
    float4 pv1 = *(const float4*)(xp + 4);
    xp += BK;
    xacc += sq8(pv0, pv1);
    *(uint4*)(lA + adst) = pack8(pv0, pv1);
  }
  float4 nv0 = *(const float4*)xp;
  float4 nv1 = *(const float4*)(xp + 4);
  xp += BK;
  asm volatile("s_waitcnt lgkmcnt(0)" ::: "memory");   // ds_writes visible
  __builtin_amdgcn_s_barrier();
  asm volatile("" ::: "memory");                       // no LDS ops hoist above

  #pragma unroll
  for (int c = 0; c < NCHUNK; ++c) {
    const uint16_t* const Acur = lA + (c & 1) * (BM * BK);
    uint16_t* const Anxt = (uint16_t*)lA + ((c & 1) ^ 1) * (BM * BK);
    const uint16_t* const bc = bl + c * 32768;

    // B kk=0 fragment loads, issued FIRST: the convert below waits on the
    // (older) x loads, which leaves these in flight (FIFO vmcnt).
    short8 b0[4];
    #pragma unroll
    for (int ni = 0; ni < 4; ++ni)
      b0[ni] = *(const short8*)(bc + ni * 512);

    // stage chunk c+1 into the other buffer (x regs issued last iteration)
    if (c < NCHUNK - 1) {
      xacc += sq8(nv0, nv1);
      *(uint4*)(Anxt + adst) = pack8(nv0, nv1);
    }

    // B kk=1 loads, then the x prefetch LAST: it is the newest VMEM op, so
    // the MFMA vmcnt waits (for b0/b1) and the barrier never drain it.
    short8 b1[4];
    #pragma unroll
    for (int ni = 0; ni < 4; ++ni)
      b1[ni] = *(const short8*)(bc + 16384 + ni * 512);
    if (c < NCHUNK - 2) {
      nv0 = *(const float4*)xp;
      nv1 = *(const float4*)(xp + 4);
      xp += BK;
    }

    // kk = 0: A frags from swizzled LDS, B frags straight from L2
    #pragma unroll
    for (int mi = 0; mi < 4; ++mi) {
      const int r = mi * 16 + p;
      short8 af = *(const short8*)(Acur + (r * 8 + (quad ^ (r & 7))) * 8);
      #pragma unroll
      for (int ni = 0; ni < 4; ++ni)
        acc[mi][ni] = __builtin_amdgcn_mfma_f32_16x16x32_bf16(
            af, b0[ni], acc[mi][ni], 0, 0, 0);
    }
    // kk = 1
    #pragma unroll
    for (int mi = 0; mi < 4; ++mi) {
      const int r = mi * 16 + p;
      short8 af = *(const short8*)(Acur + (r * 8 + ((4 + quad) ^ (r & 7))) * 8);
      #pragma unroll
      for (int ni = 0; ni < 4; ++ni)
        acc[mi][ni] = __builtin_amdgcn_mfma_f32_16x16x32_bf16(
            af, b1[ni], acc[mi][ni], 0, 0, 0);
    }

    if (c < NCHUNK - 1) {
      asm volatile("s_waitcnt lgkmcnt(0)" ::: "memory");
      __builtin_amdgcn_s_barrier();
      asm volatile("" ::: "memory");
    }
  }

  // ---- ||x||^2 per row: the 8 contributing lanes are consecutive (same wave)
  xacc += __shfl_xor(xacc, 1);
  xacc += __shfl_xor(xacc, 2);
  xacc += __shfl_xor(xacc, 4);
  if (ag == 0) lxsq[ar] = xacc;
  __syncthreads();

  // ---- epilogue: q = rcp(1 + xsq + csq - 2*dot); fused row-normalize ----
  float xs[4][4];
  #pragma unroll
  for (int mi = 0; mi < 4; ++mi)
    #pragma unroll
    for (int rr = 0; rr < 4; ++rr)
      xs[mi][rr] = lxsq[mi * 16 + quad * 4 + rr];
  float cs[4];
  #pragma unroll
  for (int ni = 0; ni < 4; ++ni)
    cs[ni] = csq[wave * 64 + ni * 16 + p];   // tiny, L2-hot

  float rp[4][4];
  #pragma unroll
  for (int mi = 0; mi < 4; ++mi)
    #pragma unroll
    for (int rr = 0; rr < 4; ++rr)
      rp[mi][rr] = 0.f;

  #pragma unroll
  for (int mi = 0; mi < 4; ++mi)
    #pragma unroll
    for (int ni = 0; ni < 4; ++ni)
      #pragma unroll
      for (int rr = 0; rr < 4; ++rr) {
        const float d = 1.0f + xs[mi][rr] + cs[ni] - 2.0f * acc[mi][ni][rr];
        const float q = __builtin_amdgcn_rcpf(d);  // d ~ 1000, 1ulp is plenty
        acc[mi][ni][rr] = q;
        rp[mi][rr] += q;
      }

  #pragma unroll
  for (int mi = 0; mi < 4; ++mi)
    #pragma unroll
    for (int rr = 0; rr < 4; ++rr) {
      float v = rp[mi][rr];
      v += __shfl_xor(v, 1);
      v += __shfl_xor(v, 2);
      v += __shfl_xor(v, 4);
      v += __shfl_xor(v, 8);
      if (p == 0) atomicAdd(&lrow[mi * 16 + quad * 4 + rr], v);
    }
  __syncthreads();

  float inv[4][4];
  #pragma unroll
  for (int mi = 0; mi < 4; ++mi)
    #pragma unroll
    for (int rr = 0; rr < 4; ++rr)
      inv[mi][rr] = __builtin_amdgcn_rcpf(lrow[mi * 16 + quad * 4 + rr]);

  // Transposed store through LDS (reusing the dead A buffers): 2 passes of
  // 32 rows; padded stride keeps write conflicts <=2-way (free); stores are
  // contiguous 1KB float4 runs per wave -> full write-combining.
  #pragma unroll
  for (int pass = 0; pass < 2; ++pass) {
    if (pass) __syncthreads();        // prior pass's reads complete
    #pragma unroll
    for (int h = 0; h < 2; ++h) {
      const int mi = pass * 2 + h;
      #pragma unroll
      for (int ni = 0; ni < 4; ++ni)
        #pragma unroll
        for (int rr = 0; rr < 4; ++rr)
          ebuf[(h * 16 + quad * 4 + rr) * ESTRIDE + wave * 64 + ni * 16 + p] =
              acc[mi][ni][rr] * inv[mi][rr];
    }
    __syncthreads();
    #pragma unroll
    for (int j = 0; j < 8; ++j) {
      const int idx = j * 512 + tid;       // 0..4095
      const int r  = idx >> 7;             // 0..31
      const int c4 = idx & 127;            // float4 column
      const float4 v = *(const float4*)&ebuf[r * ESTRIDE + c4 * 4];
      *(float4*)(out + (size_t)(row0 + pass * 32 + r) * K + c4 * 4) = v;
    }
  }
}

extern "C" void kernel_launch(void* const* d_in, const int* in_sizes, int n_in,
                              void* d_out, int out_size, void* d_ws, size_t ws_size,
                              hipStream_t stream) {
  const float* x    = (const float*)d_in[0];
  const float* cent = (const float*)d_in[1];
  float* out = (float*)d_out;

  // ws layout: csq[512] floats (2KB) | bbf bf16 image (512KB). Needs 526KB.
  float*    csq = (float*)d_ws;
  uint16_t* bbf = (uint16_t*)((char*)d_ws + 2048);

  const int N = in_sizes[0] / D;      // 65536
  prep_kernel<<<K, 64, 0, stream>>>(cent, csq, bbf);
  cluster_main<<<N / BM, THREADS, 0, stream>>>(x, bbf, csq, out);
}